// Round 10
// baseline (5227.945 us; speedup 1.0000x reference)
//
#include <hip/hip_runtime.h>

#define TT 512
#define NSTEP 511

typedef _Float16 half8v __attribute__((ext_vector_type(8)));
typedef float floatx4 __attribute__((ext_vector_type(4)));

#if __has_builtin(__builtin_amdgcn_exp2f)
#define FAST_EXP2 __builtin_amdgcn_exp2f
#else
#define FAST_EXP2 exp2f
#endif
#if __has_builtin(__builtin_amdgcn_rcpf)
#define FAST_RCP __builtin_amdgcn_rcpf
#else
#define FAST_RCP(x) (1.0f/(x))
#endif

__device__ __forceinline__ float fast_tanh(float x) {
    float e = FAST_EXP2(x * 2.885390081777927f);
    return 1.0f - 2.0f * FAST_RCP(1.0f + e);
}

__device__ __forceinline__ void split_f16(float x, _Float16& hi, _Float16& lo) {
    hi = (_Float16)x;
    lo = (_Float16)(x - (float)hi);   // exact residual, then f16 round
}

// Pack 4 f32 -> hi uint2 (4×f16) + lo uint2 (4×f16 residuals) via
// v_cvt_pkrtz_f16_f32. RTZ on hi is fine: lo absorbs hi's rounding exactly.
__device__ __forceinline__ void split_pack4(const float x0, const float x1,
                                            const float x2, const float x3,
                                            uint2& uH, uint2& uL) {
    auto h01 = __builtin_amdgcn_cvt_pkrtz(x0, x1);   // __fp16 x2
    auto h23 = __builtin_amdgcn_cvt_pkrtz(x2, x3);
    auto l01 = __builtin_amdgcn_cvt_pkrtz(x0 - (float)h01[0], x1 - (float)h01[1]);
    auto l23 = __builtin_amdgcn_cvt_pkrtz(x2 - (float)h23[0], x3 - (float)h23[1]);
    uH.x = __builtin_bit_cast(unsigned int, h01);
    uH.y = __builtin_bit_cast(unsigned int, h23);
    uL.x = __builtin_bit_cast(unsigned int, l01);
    uL.y = __builtin_bit_cast(unsigned int, l23);
}

// r10: BARRIER-FREE single-wave tiles. Evidence r3/r8/r9 (all null): the wall
// is the per-tile serial chain (~3900 cy/stage), dominated not by issue work
// (only ~60% of the wall) but by the 3 per-stage cross-wave exchanges whose
// cost includes partner-wave arrival jitter across SIMDs. This version gives
// ONE 64-thread wave the WHOLE 16-batch tile: all 64 rows of L1/L2 (tt=0..3),
// all 96 rows of L3 (c=0..2 x hh=0..1), full 32-row state z (2 register
// halves). All exchanges become in-wave LDS transposes (ds_write -> ds_read,
// same wave; DS completes in order, compiler inserts lgkmcnt) — ZERO
// __syncthreads in the integration loop. Per-SIMD MFMA issue unchanged
// (72/stage, same matrix pipe); grid 1024 x 1 wave -> 4 blocks/CU,
// 1 wave/SIMD; VGPR ~380 fits the 512 cap (__launch_bounds__(64,1)).
// A-frag: A[m=col][k=quad*8+j]; B-frag: B[k=quad*8+j][n=col];
// C: col(N)=lane&15, row(M)=quad*4+reg. 3-way hi/lo f16 split (fp32 acc).
__global__ __launch_bounds__(64, 1)
void cde_fused(const float* __restrict__ times,
               const float* __restrict__ grads,   // (B, T, 3)
               const float* __restrict__ w1, const float* __restrict__ b1,
               const float* __restrict__ w2, const float* __restrict__ b2,
               const float* __restrict__ w3, const float* __restrict__ b3,
               const float* __restrict__ w_enc, const float* __restrict__ b_enc,
               const float* __restrict__ w_ro, const float* __restrict__ b_ro,
               float* __restrict__ out)
{
    const int tid  = threadIdx.x;      // 0..63 (one wave)
    const int col  = tid & 15;         // batch-in-tile (N) / weight row (A-m)
    const int quad = tid >> 4;         // 0..3
    const int base = blockIdx.x << 4;  // global batch base

    __shared__ __align__(16) _Float16 zbufH[16][40];   // [n][k], pad->40
    __shared__ __align__(16) _Float16 zbufL[16][40];
    __shared__ __align__(16) _Float16 h1bufH[16][72];  // [n][k], pad->72
    __shared__ __align__(16) _Float16 h1bufL[16][72];
    __shared__ __align__(16) _Float16 h2bufH[16][72];
    __shared__ __align__(16) _Float16 h2bufL[16][72];
    __shared__ __align__(16) float    dqbuf[16][4];

    // -------- weights -> f16 hi/lo A-fragments (FULL M, this wave) ---------
    half8v w1fH[4], w1fL[4];
    #pragma unroll
    for (int tt = 0; tt < 4; ++tt) {
        const float* p = w1 + (16*tt + col)*32 + quad*8;
        #pragma unroll
        for (int j = 0; j < 8; ++j) {
            _Float16 hi, lo; split_f16(p[j], hi, lo);
            w1fH[tt][j] = hi; w1fL[tt][j] = lo;
        }
    }
    half8v w2fH[4][2], w2fL[4][2];
    #pragma unroll
    for (int tt = 0; tt < 4; ++tt) {
        #pragma unroll
        for (int kt = 0; kt < 2; ++kt) {
            const float* p = w2 + (16*tt + col)*64 + kt*32 + quad*8;
            #pragma unroll
            for (int j = 0; j < 8; ++j) {
                _Float16 hi, lo; split_f16(p[j], hi, lo);
                w2fH[tt][kt][j] = hi; w2fL[tt][kt][j] = lo;
            }
        }
    }
    // L3: tile (c,hh): rows (16*hh + m)*3 + c, m = col.
    half8v w3fH[3][2][2], w3fL[3][2][2];
    #pragma unroll
    for (int c = 0; c < 3; ++c)
        #pragma unroll
        for (int hh = 0; hh < 2; ++hh)
            #pragma unroll
            for (int kt = 0; kt < 2; ++kt) {
                const float* p = w3 + ((16*hh + col)*3 + c)*64 + kt*32 + quad*8;
                #pragma unroll
                for (int j = 0; j < 8; ++j) {
                    _Float16 hi, lo; split_f16(p[j], hi, lo);
                    w3fH[c][hh][kt][j] = hi; w3fL[c][hh][kt][j] = lo;
                }
            }

    // biases in C-layout
    float b1c[4][4], b2c[4][4], b3c[3][2][4];
    #pragma unroll
    for (int tt = 0; tt < 4; ++tt)
        #pragma unroll
        for (int r = 0; r < 4; ++r) {
            b1c[tt][r] = b1[16*tt + 4*quad + r];
            b2c[tt][r] = b2[16*tt + 4*quad + r];
        }
    #pragma unroll
    for (int c = 0; c < 3; ++c)
        #pragma unroll
        for (int hh = 0; hh < 2; ++hh)
            #pragma unroll
            for (int r = 0; r < 4; ++r)
                b3c[c][hh][r] = b3[(16*hh + 4*quad + r)*3 + c];

    // full state z: half tz rows 16*tz + 4*quad + r
    float z[2][4];
    #pragma unroll
    for (int tz = 0; tz < 2; ++tz)
        #pragma unroll
        for (int r = 0; r < 4; ++r) {
            const int h = 16*tz + 4*quad + r;
            z[tz][r] = w_enc[h] + b_enc[h];   // encoder([1.0])
        }
    const float dt = times[1] - times[0];

    // dq staging: threads 0..47 fetch one (b,c) stream
    const int lcl = tid < 48 ? tid : 47;
    const int bl  = lcl / 3;
    const int cc  = lcl - 3*bl;
    const float* gp = grads + (long)(base + bl)*(TT*3) + cc;
    const bool dqact = tid < 48;
    float dqreg = gp[0];

    static constexpr float AT[6][5] = {
        {0.f, 0.f, 0.f, 0.f, 0.f},
        {0.161f, 0.f, 0.f, 0.f, 0.f},
        {-0.008480655492356989f, 0.335480655492357f, 0.f, 0.f, 0.f},
        {2.8971530571054935f, -6.359448489975075f, 4.3622954328695815f, 0.f, 0.f},
        {5.325864828439257f, -11.748883564062828f, 7.4955393428898365f,
         -0.09249506636175525f, 0.f},
        {5.86145544294642f, -12.92096931784711f, 8.159367898576159f,
         -0.071584973281401f, -0.028269050394068383f}};
    static constexpr float BT[6] = {
        0.09646076681806523f, 0.01f, 0.4798896504144996f, 1.379008574103742f,
        -3.290069515436081f, 2.324710524099774f};

    float kk[6][2][4];
    float dq0 = 0.f, dq1 = 0.f, dq2 = 0.f;

    for (int n = 0; n < NSTEP; ++n) {
        if (dqact) *(&dqbuf[0][0] + (bl*4 + cc)) = dqreg * dt;

        #pragma unroll
        for (int s = 0; s < 6; ++s) {
            // stage argument, both z-halves (in-wave transpose via LDS)
            #pragma unroll
            for (int tz = 0; tz < 2; ++tz) {
                float za[4];
                #pragma unroll
                for (int r = 0; r < 4; ++r) {
                    float v = z[tz][r];
                    #pragma unroll
                    for (int j = 0; j < s; ++j) v += AT[s][j] * kk[j][tz][r];
                    za[r] = v;
                }
                uint2 uH, uL;
                split_pack4(za[0], za[1], za[2], za[3], uH, uL);
                *(uint2*)&zbufH[col][16*tz + 4*quad] = uH;
                *(uint2*)&zbufL[col][16*tz + 4*quad] = uL;
            }
            if (s == 0) {
                const float4 dv = *(const float4*)&dqbuf[col][0];
                dq0 = dv.x; dq1 = dv.y; dq2 = dv.z;
                const int nn = (n + 1 < NSTEP) ? (n + 1) : (NSTEP - 1);
                dqreg = gp[nn * 3];          // prefetch next step's gradient
            }
            const half8v zfH = *(const half8v*)&zbufH[col][quad*8];
            const half8v zfL = *(const half8v*)&zbufL[col][quad*8];

            // ---- layer 1: all 64 rows ----
            #pragma unroll
            for (int tt = 0; tt < 4; ++tt) {
                floatx4 acc = {b1c[tt][0], b1c[tt][1], b1c[tt][2], b1c[tt][3]};
                acc = __builtin_amdgcn_mfma_f32_16x16x32_f16(w1fH[tt], zfH, acc, 0, 0, 0);
                acc = __builtin_amdgcn_mfma_f32_16x16x32_f16(w1fL[tt], zfH, acc, 0, 0, 0);
                acc = __builtin_amdgcn_mfma_f32_16x16x32_f16(w1fH[tt], zfL, acc, 0, 0, 0);
                uint2 uH, uL;
                split_pack4(fast_tanh(acc[0]), fast_tanh(acc[1]),
                            fast_tanh(acc[2]), fast_tanh(acc[3]), uH, uL);
                *(uint2*)&h1bufH[col][16*tt + 4*quad] = uH;
                *(uint2*)&h1bufL[col][16*tt + 4*quad] = uL;
            }
            const half8v h1f0H = *(const half8v*)&h1bufH[col][quad*8];
            const half8v h1f1H = *(const half8v*)&h1bufH[col][32 + quad*8];
            const half8v h1f0L = *(const half8v*)&h1bufL[col][quad*8];
            const half8v h1f1L = *(const half8v*)&h1bufL[col][32 + quad*8];

            // ---- layer 2: all 64 rows ----
            #pragma unroll
            for (int tt = 0; tt < 4; ++tt) {
                floatx4 acc = {b2c[tt][0], b2c[tt][1], b2c[tt][2], b2c[tt][3]};
                acc = __builtin_amdgcn_mfma_f32_16x16x32_f16(w2fH[tt][0], h1f0H, acc, 0, 0, 0);
                acc = __builtin_amdgcn_mfma_f32_16x16x32_f16(w2fL[tt][0], h1f0H, acc, 0, 0, 0);
                acc = __builtin_amdgcn_mfma_f32_16x16x32_f16(w2fH[tt][0], h1f0L, acc, 0, 0, 0);
                acc = __builtin_amdgcn_mfma_f32_16x16x32_f16(w2fH[tt][1], h1f1H, acc, 0, 0, 0);
                acc = __builtin_amdgcn_mfma_f32_16x16x32_f16(w2fL[tt][1], h1f1H, acc, 0, 0, 0);
                acc = __builtin_amdgcn_mfma_f32_16x16x32_f16(w2fH[tt][1], h1f1L, acc, 0, 0, 0);
                uint2 uH, uL;
                split_pack4(fast_tanh(acc[0]), fast_tanh(acc[1]),
                            fast_tanh(acc[2]), fast_tanh(acc[3]), uH, uL);
                *(uint2*)&h2bufH[col][16*tt + 4*quad] = uH;
                *(uint2*)&h2bufL[col][16*tt + 4*quad] = uL;
            }
            const half8v h2f0H = *(const half8v*)&h2bufH[col][quad*8];
            const half8v h2f1H = *(const half8v*)&h2bufH[col][32 + quad*8];
            const half8v h2f0L = *(const half8v*)&h2bufL[col][quad*8];
            const half8v h2f1L = *(const half8v*)&h2bufL[col][32 + quad*8];

            // ---- layer 3: all 96 rows (c x hh), dq-contract to kk ----
            #pragma unroll
            for (int hh = 0; hh < 2; ++hh) {
                floatx4 a3[3];
                #pragma unroll
                for (int c = 0; c < 3; ++c) {
                    floatx4 acc = {b3c[c][hh][0], b3c[c][hh][1],
                                   b3c[c][hh][2], b3c[c][hh][3]};
                    acc = __builtin_amdgcn_mfma_f32_16x16x32_f16(w3fH[c][hh][0], h2f0H, acc, 0, 0, 0);
                    acc = __builtin_amdgcn_mfma_f32_16x16x32_f16(w3fL[c][hh][0], h2f0H, acc, 0, 0, 0);
                    acc = __builtin_amdgcn_mfma_f32_16x16x32_f16(w3fH[c][hh][0], h2f0L, acc, 0, 0, 0);
                    acc = __builtin_amdgcn_mfma_f32_16x16x32_f16(w3fH[c][hh][1], h2f1H, acc, 0, 0, 0);
                    acc = __builtin_amdgcn_mfma_f32_16x16x32_f16(w3fL[c][hh][1], h2f1H, acc, 0, 0, 0);
                    acc = __builtin_amdgcn_mfma_f32_16x16x32_f16(w3fH[c][hh][1], h2f1L, acc, 0, 0, 0);
                    a3[c] = acc;
                }
                #pragma unroll
                for (int r = 0; r < 4; ++r)
                    kk[s][hh][r] = a3[0][r]*dq0 + a3[1][r]*dq1 + a3[2][r]*dq2;
            }
        }

        // z += sum_i B_i * k_i (both halves)
        #pragma unroll
        for (int tz = 0; tz < 2; ++tz)
            #pragma unroll
            for (int r = 0; r < 4; ++r) {
                float v = z[tz][r];
                #pragma unroll
                for (int j = 0; j < 6; ++j) v += BT[j] * kk[j][tz][r];
                z[tz][r] = v;
            }
    }

    // ---- readout: logit[b] = sum_h z[h][b]*w_ro[h] + b_ro; out = sigmoid ----
    float part = 0.f;
    #pragma unroll
    for (int tz = 0; tz < 2; ++tz)
        #pragma unroll
        for (int r = 0; r < 4; ++r)
            part += z[tz][r] * w_ro[16*tz + 4*quad + r];
    part += __shfl_xor(part, 16, 64);
    part += __shfl_xor(part, 32, 64);
    if (tid < 16) {
        const float x = part + b_ro[0];
        out[base + col] = FAST_RCP(1.0f + FAST_EXP2(-1.4426950408889634f * x));
    }
}

extern "C" void kernel_launch(void* const* d_in, const int* in_sizes, int n_in,
                              void* d_out, int out_size, void* d_ws, size_t ws_size,
                              hipStream_t stream) {
    const float* times = (const float*)d_in[0];
    const float* grads = (const float*)d_in[1];
    const float* w1    = (const float*)d_in[2];
    const float* b1    = (const float*)d_in[3];
    const float* w2    = (const float*)d_in[4];
    const float* b2    = (const float*)d_in[5];
    const float* w3    = (const float*)d_in[6];
    const float* b3    = (const float*)d_in[7];
    const float* w_enc = (const float*)d_in[8];
    const float* b_enc = (const float*)d_in[9];
    const float* w_ro  = (const float*)d_in[10];
    const float* b_ro  = (const float*)d_in[11];

    const int B = in_sizes[1] / (TT * 3);   // 16384
    dim3 grid(B / 16), block(64);
    hipLaunchKernelGGL(cde_fused, grid, block, 0, stream,
                       times, grads, w1, b1, w2, b2, w3, b3,
                       w_enc, b_enc, w_ro, b_ro, (float*)d_out);
}

// Round 11
// 4358.910 us; speedup vs baseline: 1.1994x; 1.1994x over previous
//
#include <hip/hip_runtime.h>

#define TT 512
#define NSTEP 511

typedef _Float16 half8v __attribute__((ext_vector_type(8)));
typedef float floatx4 __attribute__((ext_vector_type(4)));

#if __has_builtin(__builtin_amdgcn_exp2f)
#define FAST_EXP2 __builtin_amdgcn_exp2f
#else
#define FAST_EXP2 exp2f
#endif
#if __has_builtin(__builtin_amdgcn_rcpf)
#define FAST_RCP __builtin_amdgcn_rcpf
#else
#define FAST_RCP(x) (1.0f/(x))
#endif

__device__ __forceinline__ float fast_tanh(float x) {
    float e = FAST_EXP2(x * 2.885390081777927f);
    return 1.0f - 2.0f * FAST_RCP(1.0f + e);
}

__device__ __forceinline__ void split_f16(float x, _Float16& hi, _Float16& lo) {
    hi = (_Float16)x;
    lo = (_Float16)(x - (float)hi);   // exact residual, then f16 round
}

// Pack 4 f32 -> hi uint2 (4×f16) + lo uint2 (4×f16 residuals) via
// v_cvt_pkrtz_f16_f32. RTZ on hi is fine: lo absorbs hi's rounding exactly.
__device__ __forceinline__ void split_pack4(const float x0, const float x1,
                                            const float x2, const float x3,
                                            uint2& uH, uint2& uL) {
    auto h01 = __builtin_amdgcn_cvt_pkrtz(x0, x1);   // __fp16 x2
    auto h23 = __builtin_amdgcn_cvt_pkrtz(x2, x3);
    auto l01 = __builtin_amdgcn_cvt_pkrtz(x0 - (float)h01[0], x1 - (float)h01[1]);
    auto l23 = __builtin_amdgcn_cvt_pkrtz(x2 - (float)h23[0], x3 - (float)h23[1]);
    uH.x = __builtin_bit_cast(unsigned int, h01);
    uH.y = __builtin_bit_cast(unsigned int, h23);
    uL.x = __builtin_bit_cast(unsigned int, l01);
    uL.y = __builtin_bit_cast(unsigned int, l23);
}

// r11: SPLIT-BURST barriers on the r5 skeleton (best: 4420 µs).
// Evidence: r10 (barrier-free, 1 wave/SIMD) was WORSE -> idle is exposed
// dependency latency, partially filled by the 2nd wave/SIMD in r5. This
// version moves half of each L2/L3 MFMA burst BEFORE the barrier: the K=32
// chunks of h1/h2 split exactly on wave ownership (rows 32*wid.. are this
// wave's own LDS writes, readable pre-barrier via same-wave DS ordering —
// validated in r10). Schedule per stage:
//   za+write | B0 | L1 (K=32, unsplittable) + epilogue + h1-own writes
//   L2-own-chunk MFMAs | B1 | L2-other + epilogue + h2-own writes
//   L3-own-chunk MFMAs | B2 | L3-other + dq-contract
// Partner skew at B1/B2 is absorbed by pre-barrier MFMA work instead of
// being fully exposed. Same FLOPs, same 3 barriers, weights re-indexed
// own/other (wave-uniform at init, static register names in the loop).
// A-frag: A[m=lane&15][k=quad*8+j]; B-frag: B[k=quad*8+j][n=lane&15];
// C: col(N)=lane&15, row(M)=quad*4+reg. 3-way hi/lo f16 split (fp32 acc).
__global__ __launch_bounds__(128, 2)
void cde_fused(const float* __restrict__ times,
               const float* __restrict__ grads,   // (B, T, 3)
               const float* __restrict__ w1, const float* __restrict__ b1,
               const float* __restrict__ w2, const float* __restrict__ b2,
               const float* __restrict__ w3, const float* __restrict__ b3,
               const float* __restrict__ w_enc, const float* __restrict__ b_enc,
               const float* __restrict__ w_ro, const float* __restrict__ b_ro,
               float* __restrict__ out)
{
    const int tid  = threadIdx.x;      // 0..127
    const int wid  = tid >> 6;         // wave id: 0,1
    const int lane = tid & 63;
    const int col  = lane & 15;        // batch-in-tile (N) / weight row (A-m)
    const int quad = lane >> 4;        // 0..3
    const int base = blockIdx.x << 4;  // global batch base
    const int own  = wid;              // own K-chunk of h1/h2 (rows 32*wid..)
    const int oth  = 1 - wid;

    __shared__ __align__(16) _Float16 zbufH[16][40];   // [n][k], pad->40
    __shared__ __align__(16) _Float16 zbufL[16][40];
    __shared__ __align__(16) _Float16 h1bufH[16][72];  // [n][k], pad->72
    __shared__ __align__(16) _Float16 h1bufL[16][72];
    __shared__ __align__(16) _Float16 h2bufH[16][72];
    __shared__ __align__(16) _Float16 h2bufL[16][72];
    __shared__ __align__(16) float    dqbuf[16][4];
    __shared__ float robuf[16];

    // -------- weights -> f16 hi/lo A-fragments (this wave's halves) ---------
    half8v w1fH[2], w1fL[2];
    #pragma unroll
    for (int tt = 0; tt < 2; ++tt) {
        const int T = 2*wid + tt;
        const float* p = w1 + (16*T + col)*32 + quad*8;
        #pragma unroll
        for (int j = 0; j < 8; ++j) {
            _Float16 hi, lo; split_f16(p[j], hi, lo);
            w1fH[tt][j] = hi; w1fL[tt][j] = lo;
        }
    }
    // L2: own/other K-chunks (own = rows 32*wid of h1, i.e. kt = wid)
    half8v w2oH[2], w2oL[2], w2xH[2], w2xL[2];
    #pragma unroll
    for (int tt = 0; tt < 2; ++tt) {
        const int T = 2*wid + tt;
        {
            const float* p = w2 + (16*T + col)*64 + own*32 + quad*8;
            #pragma unroll
            for (int j = 0; j < 8; ++j) {
                _Float16 hi, lo; split_f16(p[j], hi, lo);
                w2oH[tt][j] = hi; w2oL[tt][j] = lo;
            }
        }
        {
            const float* p = w2 + (16*T + col)*64 + oth*32 + quad*8;
            #pragma unroll
            for (int j = 0; j < 8; ++j) {
                _Float16 hi, lo; split_f16(p[j], hi, lo);
                w2xH[tt][j] = hi; w2xL[tt][j] = lo;
            }
        }
    }
    // L3: rows (16*wid + col)*3 + c; own/other K-chunks of h2
    half8v w3oH[3], w3oL[3], w3xH[3], w3xL[3];
    #pragma unroll
    for (int c = 0; c < 3; ++c) {
        const int row = (16*wid + col)*3 + c;
        {
            const float* p = w3 + row*64 + own*32 + quad*8;
            #pragma unroll
            for (int j = 0; j < 8; ++j) {
                _Float16 hi, lo; split_f16(p[j], hi, lo);
                w3oH[c][j] = hi; w3oL[c][j] = lo;
            }
        }
        {
            const float* p = w3 + row*64 + oth*32 + quad*8;
            #pragma unroll
            for (int j = 0; j < 8; ++j) {
                _Float16 hi, lo; split_f16(p[j], hi, lo);
                w3xH[c][j] = hi; w3xL[c][j] = lo;
            }
        }
    }

    // biases in C-layout
    float b1c[2][4], b2c[2][4], b3c[3][4];
    #pragma unroll
    for (int tt = 0; tt < 2; ++tt) {
        const int T = 2*wid + tt;
        #pragma unroll
        for (int r = 0; r < 4; ++r) {
            b1c[tt][r] = b1[16*T + 4*quad + r];
            b2c[tt][r] = b2[16*T + 4*quad + r];
        }
    }
    #pragma unroll
    for (int c = 0; c < 3; ++c)
        #pragma unroll
        for (int r = 0; r < 4; ++r)
            b3c[c][r] = b3[(16*wid + 4*quad + r)*3 + c];

    // state z rows owned by this wave: h = 16*wid + 4*quad + r
    float z[4];
    #pragma unroll
    for (int r = 0; r < 4; ++r) {
        const int h = 16*wid + 4*quad + r;
        z[r] = w_enc[h] + b_enc[h];   // encoder([1.0])
    }
    const float dt = times[1] - times[0];

    // dq staging: threads 0..47 (wave 0) fetch one (b,c) stream
    const int lcl = tid < 48 ? tid : 47;
    const int bl  = lcl / 3;
    const int cc  = lcl - 3*bl;
    const float* gp = grads + (long)(base + bl)*(TT*3) + cc;
    const bool dqact = tid < 48;
    float dqreg = gp[0];

    static constexpr float AT[6][5] = {
        {0.f, 0.f, 0.f, 0.f, 0.f},
        {0.161f, 0.f, 0.f, 0.f, 0.f},
        {-0.008480655492356989f, 0.335480655492357f, 0.f, 0.f, 0.f},
        {2.8971530571054935f, -6.359448489975075f, 4.3622954328695815f, 0.f, 0.f},
        {5.325864828439257f, -11.748883564062828f, 7.4955393428898365f,
         -0.09249506636175525f, 0.f},
        {5.86145544294642f, -12.92096931784711f, 8.159367898576159f,
         -0.071584973281401f, -0.028269050394068383f}};
    static constexpr float BT[6] = {
        0.09646076681806523f, 0.01f, 0.4798896504144996f, 1.379008574103742f,
        -3.290069515436081f, 2.324710524099774f};

    float kk[6][4];
    float dq0 = 0.f, dq1 = 0.f, dq2 = 0.f;

    for (int n = 0; n < NSTEP; ++n) {
        if (dqact) *(&dqbuf[0][0] + (bl*4 + cc)) = dqreg * dt;

        #pragma unroll
        for (int s = 0; s < 6; ++s) {
            // ---- za (own 16 z rows) + publish ----
            float za[4];
            #pragma unroll
            for (int r = 0; r < 4; ++r) {
                float v = z[r];
                #pragma unroll
                for (int j = 0; j < s; ++j) v += AT[s][j] * kk[j][r];
                za[r] = v;
            }
            {
                uint2 uH, uL;
                split_pack4(za[0], za[1], za[2], za[3], uH, uL);
                *(uint2*)&zbufH[col][16*wid + 4*quad] = uH;
                *(uint2*)&zbufL[col][16*wid + 4*quad] = uL;
            }
            __syncthreads();                                   // B0: za ready
            if (s == 0) {
                const float4 dv = *(const float4*)&dqbuf[col][0];
                dq0 = dv.x; dq1 = dv.y; dq2 = dv.z;
                const int nn = (n + 1 < NSTEP) ? (n + 1) : (NSTEP - 1);
                dqreg = gp[nn * 3];          // prefetch next step's gradient
            }
            const half8v zfH = *(const half8v*)&zbufH[col][quad*8];
            const half8v zfL = *(const half8v*)&zbufL[col][quad*8];

            // ---- layer 1 (K=32, unsplittable): this wave's 32 rows ----
            #pragma unroll
            for (int tt = 0; tt < 2; ++tt) {
                floatx4 acc = {b1c[tt][0], b1c[tt][1], b1c[tt][2], b1c[tt][3]};
                acc = __builtin_amdgcn_mfma_f32_16x16x32_f16(w1fH[tt], zfH, acc, 0, 0, 0);
                acc = __builtin_amdgcn_mfma_f32_16x16x32_f16(w1fL[tt], zfH, acc, 0, 0, 0);
                acc = __builtin_amdgcn_mfma_f32_16x16x32_f16(w1fH[tt], zfL, acc, 0, 0, 0);
                uint2 uH, uL;
                split_pack4(fast_tanh(acc[0]), fast_tanh(acc[1]),
                            fast_tanh(acc[2]), fast_tanh(acc[3]), uH, uL);
                *(uint2*)&h1bufH[col][32*wid + 16*tt + 4*quad] = uH;
                *(uint2*)&h1bufL[col][32*wid + 16*tt + 4*quad] = uL;
            }
            // ---- layer 2, OWN K-chunk (own h1 writes: same-wave DS order) ----
            const half8v h1oH = *(const half8v*)&h1bufH[col][32*own + quad*8];
            const half8v h1oL = *(const half8v*)&h1bufL[col][32*own + quad*8];
            floatx4 acc2[2];
            #pragma unroll
            for (int tt = 0; tt < 2; ++tt) {
                floatx4 acc = {b2c[tt][0], b2c[tt][1], b2c[tt][2], b2c[tt][3]};
                acc = __builtin_amdgcn_mfma_f32_16x16x32_f16(w2oH[tt], h1oH, acc, 0, 0, 0);
                acc = __builtin_amdgcn_mfma_f32_16x16x32_f16(w2oL[tt], h1oH, acc, 0, 0, 0);
                acc = __builtin_amdgcn_mfma_f32_16x16x32_f16(w2oH[tt], h1oL, acc, 0, 0, 0);
                acc2[tt] = acc;
            }
            __syncthreads();                                   // B1: h1 ready
            // ---- layer 2, OTHER K-chunk + epilogue ----
            const half8v h1xH = *(const half8v*)&h1bufH[col][32*oth + quad*8];
            const half8v h1xL = *(const half8v*)&h1bufL[col][32*oth + quad*8];
            #pragma unroll
            for (int tt = 0; tt < 2; ++tt) {
                floatx4 acc = acc2[tt];
                acc = __builtin_amdgcn_mfma_f32_16x16x32_f16(w2xH[tt], h1xH, acc, 0, 0, 0);
                acc = __builtin_amdgcn_mfma_f32_16x16x32_f16(w2xL[tt], h1xH, acc, 0, 0, 0);
                acc = __builtin_amdgcn_mfma_f32_16x16x32_f16(w2xH[tt], h1xL, acc, 0, 0, 0);
                uint2 uH, uL;
                split_pack4(fast_tanh(acc[0]), fast_tanh(acc[1]),
                            fast_tanh(acc[2]), fast_tanh(acc[3]), uH, uL);
                *(uint2*)&h2bufH[col][32*wid + 16*tt + 4*quad] = uH;
                *(uint2*)&h2bufL[col][32*wid + 16*tt + 4*quad] = uL;
            }
            // ---- layer 3, OWN K-chunk ----
            const half8v h2oH = *(const half8v*)&h2bufH[col][32*own + quad*8];
            const half8v h2oL = *(const half8v*)&h2bufL[col][32*own + quad*8];
            floatx4 acc3[3];
            #pragma unroll
            for (int c = 0; c < 3; ++c) {
                floatx4 acc = {b3c[c][0], b3c[c][1], b3c[c][2], b3c[c][3]};
                acc = __builtin_amdgcn_mfma_f32_16x16x32_f16(w3oH[c], h2oH, acc, 0, 0, 0);
                acc = __builtin_amdgcn_mfma_f32_16x16x32_f16(w3oL[c], h2oH, acc, 0, 0, 0);
                acc = __builtin_amdgcn_mfma_f32_16x16x32_f16(w3oH[c], h2oL, acc, 0, 0, 0);
                acc3[c] = acc;
            }
            __syncthreads();                                   // B2: h2 ready
            // ---- layer 3, OTHER K-chunk + dq contract ----
            const half8v h2xH = *(const half8v*)&h2bufH[col][32*oth + quad*8];
            const half8v h2xL = *(const half8v*)&h2bufL[col][32*oth + quad*8];
            floatx4 a3[3];
            #pragma unroll
            for (int c = 0; c < 3; ++c) {
                floatx4 acc = acc3[c];
                acc = __builtin_amdgcn_mfma_f32_16x16x32_f16(w3xH[c], h2xH, acc, 0, 0, 0);
                acc = __builtin_amdgcn_mfma_f32_16x16x32_f16(w3xL[c], h2xH, acc, 0, 0, 0);
                acc = __builtin_amdgcn_mfma_f32_16x16x32_f16(w3xH[c], h2xL, acc, 0, 0, 0);
                a3[c] = acc;
            }
            #pragma unroll
            for (int r = 0; r < 4; ++r)
                kk[s][r] = a3[0][r]*dq0 + a3[1][r]*dq1 + a3[2][r]*dq2;
        }

        // z += sum_i B_i * k_i
        #pragma unroll
        for (int r = 0; r < 4; ++r) {
            float v = z[r];
            #pragma unroll
            for (int j = 0; j < 6; ++j) v += BT[j] * kk[j][r];
            z[r] = v;
        }
    }

    // ---- readout: logit[b] = sum_h z[h][b]*w_ro[h] + b_ro; out = sigmoid ----
    float part = 0.f;
    #pragma unroll
    for (int r = 0; r < 4; ++r)
        part += z[r] * w_ro[16*wid + 4*quad + r];
    part += __shfl_xor(part, 16, 64);
    part += __shfl_xor(part, 32, 64);
    if (wid == 1 && lane < 16) robuf[col] = part;
    __syncthreads();
    if (wid == 0 && lane < 16) {
        const float x = part + robuf[col] + b_ro[0];
        out[base + col] = FAST_RCP(1.0f + FAST_EXP2(-1.4426950408889634f * x));
    }
}

extern "C" void kernel_launch(void* const* d_in, const int* in_sizes, int n_in,
                              void* d_out, int out_size, void* d_ws, size_t ws_size,
                              hipStream_t stream) {
    const float* times = (const float*)d_in[0];
    const float* grads = (const float*)d_in[1];
    const float* w1    = (const float*)d_in[2];
    const float* b1    = (const float*)d_in[3];
    const float* w2    = (const float*)d_in[4];
    const float* b2    = (const float*)d_in[5];
    const float* w3    = (const float*)d_in[6];
    const float* b3    = (const float*)d_in[7];
    const float* w_enc = (const float*)d_in[8];
    const float* b_enc = (const float*)d_in[9];
    const float* w_ro  = (const float*)d_in[10];
    const float* b_ro  = (const float*)d_in[11];

    const int B = in_sizes[1] / (TT * 3);   // 16384
    dim3 grid(B / 16), block(128);
    hipLaunchKernelGGL(cde_fused, grid, block, 0, stream,
                       times, grads, w1, b1, w2, b2, w3, b3,
                       w_enc, b_enc, w_ro, b_ro, (float*)d_out);
}

// Round 12
// 4202.835 us; speedup vs baseline: 1.2439x; 1.0371x over previous
//
#include <hip/hip_runtime.h>

#define TT 512
#define NSTEP 511

typedef _Float16 half8v __attribute__((ext_vector_type(8)));
typedef float floatx4 __attribute__((ext_vector_type(4)));

#if __has_builtin(__builtin_amdgcn_exp2f)
#define FAST_EXP2 __builtin_amdgcn_exp2f
#else
#define FAST_EXP2 exp2f
#endif
#if __has_builtin(__builtin_amdgcn_rcpf)
#define FAST_RCP __builtin_amdgcn_rcpf
#else
#define FAST_RCP(x) (1.0f/(x))
#endif

__device__ __forceinline__ float fast_tanh(float x) {
    float e = FAST_EXP2(x * 2.885390081777927f);
    return 1.0f - 2.0f * FAST_RCP(1.0f + e);
}

__device__ __forceinline__ void split_f16(float x, _Float16& hi, _Float16& lo) {
    hi = (_Float16)x;
    lo = (_Float16)(x - (float)hi);   // exact residual, then f16 round
}

// Pack 4 f32 -> hi uint2 (4×f16) + lo uint2 (4×f16 residuals) via
// v_cvt_pkrtz_f16_f32. RTZ on hi is fine: lo absorbs hi's rounding exactly.
__device__ __forceinline__ void split_pack4(const float x0, const float x1,
                                            const float x2, const float x3,
                                            uint2& uH, uint2& uL) {
    auto h01 = __builtin_amdgcn_cvt_pkrtz(x0, x1);   // __fp16 x2
    auto h23 = __builtin_amdgcn_cvt_pkrtz(x2, x3);
    auto l01 = __builtin_amdgcn_cvt_pkrtz(x0 - (float)h01[0], x1 - (float)h01[1]);
    auto l23 = __builtin_amdgcn_cvt_pkrtz(x2 - (float)h23[0], x3 - (float)h23[1]);
    uH.x = __builtin_bit_cast(unsigned int, h01);
    uH.y = __builtin_bit_cast(unsigned int, h23);
    uL.x = __builtin_bit_cast(unsigned int, l01);
    uL.y = __builtin_bit_cast(unsigned int, l23);
}

// r12: STRADDLED split-burst + setprio, on the r11 skeleton (best: 4359 µs).
// r11 lesson: putting ALL own-chunk MFMAs before the barrier leaves the
// post-barrier partner ds_reads with nothing to hide under (compiler cannot
// hoist across s_barrier). Now the own-chunk burst STRADDLES the barrier:
//   pre-B:  a slice of own-chunk MFMAs   (absorbs partner arrival skew)
//   post-B: issue partner ds_reads, then the REMAINING own-chunk MFMAs
//           (independent of those reads -> ~120cy read latency covered),
//           then partner-chunk MFMAs.
// B1: pre=L2-own tt0 | post=reads, L2-own tt1, L2-oth tt0/1.
// B2: pre=L3-own c0  | post=reads, L3-own c1/2, L3-oth c0..2.
// Plus s_setprio(1) around MFMA clusters: 2 waves/SIMD are from DIFFERENT
// blocks (naturally phase-skewed, attn-like regime -> m191 +4-7%, not the
// lockstep-GEMM null of m190).
// A-frag: A[m=lane&15][k=quad*8+j]; B-frag: B[k=quad*8+j][n=lane&15];
// C: col(N)=lane&15, row(M)=quad*4+reg. 3-way hi/lo f16 split (fp32 acc).
__global__ __launch_bounds__(128, 2)
void cde_fused(const float* __restrict__ times,
               const float* __restrict__ grads,   // (B, T, 3)
               const float* __restrict__ w1, const float* __restrict__ b1,
               const float* __restrict__ w2, const float* __restrict__ b2,
               const float* __restrict__ w3, const float* __restrict__ b3,
               const float* __restrict__ w_enc, const float* __restrict__ b_enc,
               const float* __restrict__ w_ro, const float* __restrict__ b_ro,
               float* __restrict__ out)
{
    const int tid  = threadIdx.x;      // 0..127
    const int wid  = tid >> 6;         // wave id: 0,1
    const int lane = tid & 63;
    const int col  = lane & 15;        // batch-in-tile (N) / weight row (A-m)
    const int quad = lane >> 4;        // 0..3
    const int base = blockIdx.x << 4;  // global batch base
    const int own  = wid;              // own K-chunk of h1/h2 (rows 32*wid..)
    const int oth  = 1 - wid;

    __shared__ __align__(16) _Float16 zbufH[16][40];   // [n][k], pad->40
    __shared__ __align__(16) _Float16 zbufL[16][40];
    __shared__ __align__(16) _Float16 h1bufH[16][72];  // [n][k], pad->72
    __shared__ __align__(16) _Float16 h1bufL[16][72];
    __shared__ __align__(16) _Float16 h2bufH[16][72];
    __shared__ __align__(16) _Float16 h2bufL[16][72];
    __shared__ __align__(16) float    dqbuf[16][4];
    __shared__ float robuf[16];

    // -------- weights -> f16 hi/lo A-fragments (this wave's halves) ---------
    half8v w1fH[2], w1fL[2];
    #pragma unroll
    for (int tt = 0; tt < 2; ++tt) {
        const int T = 2*wid + tt;
        const float* p = w1 + (16*T + col)*32 + quad*8;
        #pragma unroll
        for (int j = 0; j < 8; ++j) {
            _Float16 hi, lo; split_f16(p[j], hi, lo);
            w1fH[tt][j] = hi; w1fL[tt][j] = lo;
        }
    }
    // L2: own/other K-chunks (own = rows 32*wid of h1, i.e. kt = wid)
    half8v w2oH[2], w2oL[2], w2xH[2], w2xL[2];
    #pragma unroll
    for (int tt = 0; tt < 2; ++tt) {
        const int T = 2*wid + tt;
        {
            const float* p = w2 + (16*T + col)*64 + own*32 + quad*8;
            #pragma unroll
            for (int j = 0; j < 8; ++j) {
                _Float16 hi, lo; split_f16(p[j], hi, lo);
                w2oH[tt][j] = hi; w2oL[tt][j] = lo;
            }
        }
        {
            const float* p = w2 + (16*T + col)*64 + oth*32 + quad*8;
            #pragma unroll
            for (int j = 0; j < 8; ++j) {
                _Float16 hi, lo; split_f16(p[j], hi, lo);
                w2xH[tt][j] = hi; w2xL[tt][j] = lo;
            }
        }
    }
    // L3: rows (16*wid + col)*3 + c; own/other K-chunks of h2
    half8v w3oH[3], w3oL[3], w3xH[3], w3xL[3];
    #pragma unroll
    for (int c = 0; c < 3; ++c) {
        const int row = (16*wid + col)*3 + c;
        {
            const float* p = w3 + row*64 + own*32 + quad*8;
            #pragma unroll
            for (int j = 0; j < 8; ++j) {
                _Float16 hi, lo; split_f16(p[j], hi, lo);
                w3oH[c][j] = hi; w3oL[c][j] = lo;
            }
        }
        {
            const float* p = w3 + row*64 + oth*32 + quad*8;
            #pragma unroll
            for (int j = 0; j < 8; ++j) {
                _Float16 hi, lo; split_f16(p[j], hi, lo);
                w3xH[c][j] = hi; w3xL[c][j] = lo;
            }
        }
    }

    // biases in C-layout
    float b1c[2][4], b2c[2][4], b3c[3][4];
    #pragma unroll
    for (int tt = 0; tt < 2; ++tt) {
        const int T = 2*wid + tt;
        #pragma unroll
        for (int r = 0; r < 4; ++r) {
            b1c[tt][r] = b1[16*T + 4*quad + r];
            b2c[tt][r] = b2[16*T + 4*quad + r];
        }
    }
    #pragma unroll
    for (int c = 0; c < 3; ++c)
        #pragma unroll
        for (int r = 0; r < 4; ++r)
            b3c[c][r] = b3[(16*wid + 4*quad + r)*3 + c];

    // state z rows owned by this wave: h = 16*wid + 4*quad + r
    float z[4];
    #pragma unroll
    for (int r = 0; r < 4; ++r) {
        const int h = 16*wid + 4*quad + r;
        z[r] = w_enc[h] + b_enc[h];   // encoder([1.0])
    }
    const float dt = times[1] - times[0];

    // dq staging: threads 0..47 (wave 0) fetch one (b,c) stream
    const int lcl = tid < 48 ? tid : 47;
    const int bl  = lcl / 3;
    const int cc  = lcl - 3*bl;
    const float* gp = grads + (long)(base + bl)*(TT*3) + cc;
    const bool dqact = tid < 48;
    float dqreg = gp[0];

    static constexpr float AT[6][5] = {
        {0.f, 0.f, 0.f, 0.f, 0.f},
        {0.161f, 0.f, 0.f, 0.f, 0.f},
        {-0.008480655492356989f, 0.335480655492357f, 0.f, 0.f, 0.f},
        {2.8971530571054935f, -6.359448489975075f, 4.3622954328695815f, 0.f, 0.f},
        {5.325864828439257f, -11.748883564062828f, 7.4955393428898365f,
         -0.09249506636175525f, 0.f},
        {5.86145544294642f, -12.92096931784711f, 8.159367898576159f,
         -0.071584973281401f, -0.028269050394068383f}};
    static constexpr float BT[6] = {
        0.09646076681806523f, 0.01f, 0.4798896504144996f, 1.379008574103742f,
        -3.290069515436081f, 2.324710524099774f};

    float kk[6][4];
    float dq0 = 0.f, dq1 = 0.f, dq2 = 0.f;

    for (int n = 0; n < NSTEP; ++n) {
        if (dqact) *(&dqbuf[0][0] + (bl*4 + cc)) = dqreg * dt;

        #pragma unroll
        for (int s = 0; s < 6; ++s) {
            // ---- za (own 16 z rows) + publish ----
            float za[4];
            #pragma unroll
            for (int r = 0; r < 4; ++r) {
                float v = z[r];
                #pragma unroll
                for (int j = 0; j < s; ++j) v += AT[s][j] * kk[j][r];
                za[r] = v;
            }
            {
                uint2 uH, uL;
                split_pack4(za[0], za[1], za[2], za[3], uH, uL);
                *(uint2*)&zbufH[col][16*wid + 4*quad] = uH;
                *(uint2*)&zbufL[col][16*wid + 4*quad] = uL;
            }
            __syncthreads();                                   // B0: za ready
            if (s == 0) {
                const float4 dv = *(const float4*)&dqbuf[col][0];
                dq0 = dv.x; dq1 = dv.y; dq2 = dv.z;
                const int nn = (n + 1 < NSTEP) ? (n + 1) : (NSTEP - 1);
                dqreg = gp[nn * 3];          // prefetch next step's gradient
            }
            const half8v zfH = *(const half8v*)&zbufH[col][quad*8];
            const half8v zfL = *(const half8v*)&zbufL[col][quad*8];

            // ---- layer 1 (K=32, unsplittable): this wave's 32 rows ----
            __builtin_amdgcn_s_setprio(1);
            #pragma unroll
            for (int tt = 0; tt < 2; ++tt) {
                floatx4 acc = {b1c[tt][0], b1c[tt][1], b1c[tt][2], b1c[tt][3]};
                acc = __builtin_amdgcn_mfma_f32_16x16x32_f16(w1fH[tt], zfH, acc, 0, 0, 0);
                acc = __builtin_amdgcn_mfma_f32_16x16x32_f16(w1fL[tt], zfH, acc, 0, 0, 0);
                acc = __builtin_amdgcn_mfma_f32_16x16x32_f16(w1fH[tt], zfL, acc, 0, 0, 0);
                uint2 uH, uL;
                split_pack4(fast_tanh(acc[0]), fast_tanh(acc[1]),
                            fast_tanh(acc[2]), fast_tanh(acc[3]), uH, uL);
                *(uint2*)&h1bufH[col][32*wid + 16*tt + 4*quad] = uH;
                *(uint2*)&h1bufL[col][32*wid + 16*tt + 4*quad] = uL;
            }
            // ---- layer 2, own chunk, tt=0 slice (pre-B1: absorbs skew) ----
            const half8v h1oH = *(const half8v*)&h1bufH[col][32*own + quad*8];
            const half8v h1oL = *(const half8v*)&h1bufL[col][32*own + quad*8];
            floatx4 acc2[2];
            {
                floatx4 acc = {b2c[0][0], b2c[0][1], b2c[0][2], b2c[0][3]};
                acc = __builtin_amdgcn_mfma_f32_16x16x32_f16(w2oH[0], h1oH, acc, 0, 0, 0);
                acc = __builtin_amdgcn_mfma_f32_16x16x32_f16(w2oL[0], h1oH, acc, 0, 0, 0);
                acc = __builtin_amdgcn_mfma_f32_16x16x32_f16(w2oH[0], h1oL, acc, 0, 0, 0);
                acc2[0] = acc;
            }
            __builtin_amdgcn_s_setprio(0);
            __syncthreads();                                   // B1: h1 ready
            // ---- post-B1: issue partner reads, cover with own tt=1 ----
            const half8v h1xH = *(const half8v*)&h1bufH[col][32*oth + quad*8];
            const half8v h1xL = *(const half8v*)&h1bufL[col][32*oth + quad*8];
            __builtin_amdgcn_s_setprio(1);
            {
                floatx4 acc = {b2c[1][0], b2c[1][1], b2c[1][2], b2c[1][3]};
                acc = __builtin_amdgcn_mfma_f32_16x16x32_f16(w2oH[1], h1oH, acc, 0, 0, 0);
                acc = __builtin_amdgcn_mfma_f32_16x16x32_f16(w2oL[1], h1oH, acc, 0, 0, 0);
                acc = __builtin_amdgcn_mfma_f32_16x16x32_f16(w2oH[1], h1oL, acc, 0, 0, 0);
                acc2[1] = acc;
            }
            #pragma unroll
            for (int tt = 0; tt < 2; ++tt) {
                floatx4 acc = acc2[tt];
                acc = __builtin_amdgcn_mfma_f32_16x16x32_f16(w2xH[tt], h1xH, acc, 0, 0, 0);
                acc = __builtin_amdgcn_mfma_f32_16x16x32_f16(w2xL[tt], h1xH, acc, 0, 0, 0);
                acc = __builtin_amdgcn_mfma_f32_16x16x32_f16(w2xH[tt], h1xL, acc, 0, 0, 0);
                uint2 uH, uL;
                split_pack4(fast_tanh(acc[0]), fast_tanh(acc[1]),
                            fast_tanh(acc[2]), fast_tanh(acc[3]), uH, uL);
                *(uint2*)&h2bufH[col][32*wid + 16*tt + 4*quad] = uH;
                *(uint2*)&h2bufL[col][32*wid + 16*tt + 4*quad] = uL;
            }
            // ---- layer 3, own chunk, c=0 slice (pre-B2: absorbs skew) ----
            const half8v h2oH = *(const half8v*)&h2bufH[col][32*own + quad*8];
            const half8v h2oL = *(const half8v*)&h2bufL[col][32*own + quad*8];
            floatx4 acc3[3];
            {
                floatx4 acc = {b3c[0][0], b3c[0][1], b3c[0][2], b3c[0][3]};
                acc = __builtin_amdgcn_mfma_f32_16x16x32_f16(w3oH[0], h2oH, acc, 0, 0, 0);
                acc = __builtin_amdgcn_mfma_f32_16x16x32_f16(w3oL[0], h2oH, acc, 0, 0, 0);
                acc = __builtin_amdgcn_mfma_f32_16x16x32_f16(w3oH[0], h2oL, acc, 0, 0, 0);
                acc3[0] = acc;
            }
            __builtin_amdgcn_s_setprio(0);
            __syncthreads();                                   // B2: h2 ready
            // ---- post-B2: issue partner reads, cover with own c=1,2 ----
            const half8v h2xH = *(const half8v*)&h2bufH[col][32*oth + quad*8];
            const half8v h2xL = *(const half8v*)&h2bufL[col][32*oth + quad*8];
            __builtin_amdgcn_s_setprio(1);
            #pragma unroll
            for (int c = 1; c < 3; ++c) {
                floatx4 acc = {b3c[c][0], b3c[c][1], b3c[c][2], b3c[c][3]};
                acc = __builtin_amdgcn_mfma_f32_16x16x32_f16(w3oH[c], h2oH, acc, 0, 0, 0);
                acc = __builtin_amdgcn_mfma_f32_16x16x32_f16(w3oL[c], h2oH, acc, 0, 0, 0);
                acc = __builtin_amdgcn_mfma_f32_16x16x32_f16(w3oH[c], h2oL, acc, 0, 0, 0);
                acc3[c] = acc;
            }
            #pragma unroll
            for (int c = 0; c < 3; ++c) {
                acc3[c] = __builtin_amdgcn_mfma_f32_16x16x32_f16(w3xH[c], h2xH, acc3[c], 0, 0, 0);
                acc3[c] = __builtin_amdgcn_mfma_f32_16x16x32_f16(w3xL[c], h2xH, acc3[c], 0, 0, 0);
                acc3[c] = __builtin_amdgcn_mfma_f32_16x16x32_f16(w3xH[c], h2xL, acc3[c], 0, 0, 0);
            }
            __builtin_amdgcn_s_setprio(0);
            #pragma unroll
            for (int r = 0; r < 4; ++r)
                kk[s][r] = acc3[0][r]*dq0 + acc3[1][r]*dq1 + acc3[2][r]*dq2;
        }

        // z += sum_i B_i * k_i
        #pragma unroll
        for (int r = 0; r < 4; ++r) {
            float v = z[r];
            #pragma unroll
            for (int j = 0; j < 6; ++j) v += BT[j] * kk[j][r];
            z[r] = v;
        }
    }

    // ---- readout: logit[b] = sum_h z[h][b]*w_ro[h] + b_ro; out = sigmoid ----
    float part = 0.f;
    #pragma unroll
    for (int r = 0; r < 4; ++r)
        part += z[r] * w_ro[16*wid + 4*quad + r];
    part += __shfl_xor(part, 16, 64);
    part += __shfl_xor(part, 32, 64);
    if (wid == 1 && lane < 16) robuf[col] = part;
    __syncthreads();
    if (wid == 0 && lane < 16) {
        const float x = part + robuf[col] + b_ro[0];
        out[base + col] = FAST_RCP(1.0f + FAST_EXP2(-1.4426950408889634f * x));
    }
}

extern "C" void kernel_launch(void* const* d_in, const int* in_sizes, int n_in,
                              void* d_out, int out_size, void* d_ws, size_t ws_size,
                              hipStream_t stream) {
    const float* times = (const float*)d_in[0];
    const float* grads = (const float*)d_in[1];
    const float* w1    = (const float*)d_in[2];
    const float* b1    = (const float*)d_in[3];
    const float* w2    = (const float*)d_in[4];
    const float* b2    = (const float*)d_in[5];
    const float* w3    = (const float*)d_in[6];
    const float* b3    = (const float*)d_in[7];
    const float* w_enc = (const float*)d_in[8];
    const float* b_enc = (const float*)d_in[9];
    const float* w_ro  = (const float*)d_in[10];
    const float* b_ro  = (const float*)d_in[11];

    const int B = in_sizes[1] / (TT * 3);   // 16384
    dim3 grid(B / 16), block(128);
    hipLaunchKernelGGL(cde_fused, grid, block, 0, stream,
                       times, grads, w1, b1, w2, b2, w3, b3,
                       w_enc, b_enc, w_ro, b_ro, (float*)d_out);
}

// Round 13
// 4193.066 us; speedup vs baseline: 1.2468x; 1.0023x over previous
//
#include <hip/hip_runtime.h>

#define TT 512
#define NSTEP 511

typedef _Float16 half8v __attribute__((ext_vector_type(8)));
typedef float floatx4 __attribute__((ext_vector_type(4)));

#if __has_builtin(__builtin_amdgcn_exp2f)
#define FAST_EXP2 __builtin_amdgcn_exp2f
#else
#define FAST_EXP2 exp2f
#endif
#if __has_builtin(__builtin_amdgcn_rcpf)
#define FAST_RCP __builtin_amdgcn_rcpf
#else
#define FAST_RCP(x) (1.0f/(x))
#endif

__device__ __forceinline__ float fast_tanh(float x) {
    float e = FAST_EXP2(x * 2.885390081777927f);
    return 1.0f - 2.0f * FAST_RCP(1.0f + e);
}

__device__ __forceinline__ void split_f16(float x, _Float16& hi, _Float16& lo) {
    hi = (_Float16)x;
    lo = (_Float16)(x - (float)hi);   // exact residual, then f16 round
}

// Pack 4 f32 -> hi uint2 (4×f16) + lo uint2 (4×f16 residuals) via
// v_cvt_pkrtz_f16_f32. RTZ on hi is fine: lo absorbs hi's rounding exactly.
__device__ __forceinline__ void split_pack4(const float x0, const float x1,
                                            const float x2, const float x3,
                                            uint2& uH, uint2& uL) {
    auto h01 = __builtin_amdgcn_cvt_pkrtz(x0, x1);   // __fp16 x2
    auto h23 = __builtin_amdgcn_cvt_pkrtz(x2, x3);
    auto l01 = __builtin_amdgcn_cvt_pkrtz(x0 - (float)h01[0], x1 - (float)h01[1]);
    auto l23 = __builtin_amdgcn_cvt_pkrtz(x2 - (float)h23[0], x3 - (float)h23[1]);
    uH.x = __builtin_bit_cast(unsigned int, h01);
    uH.y = __builtin_bit_cast(unsigned int, h23);
    uL.x = __builtin_bit_cast(unsigned int, l01);
    uL.y = __builtin_bit_cast(unsigned int, l23);
}

// r13: CHUNK-MAJOR LDS layout on the r12 skeleton (best: 4203 µs).
// r12 counters: SQ_LDS_BANK_CONFLICT = 5.03e8 ≈ 17% of wall cycles/CU. The
// [n][k] layout's fragment read (&buf[col][quad*8], 144B row stride) maps to
// bank group 4(col+quad)%32 -> 8 lanes alias each group (the +8 pad never
// fixed b128 reads). New layout [kc][n][8] (kc=k/8): fragment read addr =
// lane*16 + const -> canonical conflict-free linear pattern. Epilogue write
// &buf[4wid+2tt+(quad>>1)][col][4(quad&1)] -> 4 claims/bank = balanced
// minimum (same as before). zbuf likewise ([kc=quad][col][0] on read).
// Own-chunk kc ranges stay within this wave's writes (same-wave DS order
// preserved). Schedule/straddle/setprio unchanged from r12.
// A-frag: A[m=lane&15][k=quad*8+j]; B-frag: B[k=quad*8+j][n=lane&15];
// C: col(N)=lane&15, row(M)=quad*4+reg. 3-way hi/lo f16 split (fp32 acc).
__global__ __launch_bounds__(128, 2)
void cde_fused(const float* __restrict__ times,
               const float* __restrict__ grads,   // (B, T, 3)
               const float* __restrict__ w1, const float* __restrict__ b1,
               const float* __restrict__ w2, const float* __restrict__ b2,
               const float* __restrict__ w3, const float* __restrict__ b3,
               const float* __restrict__ w_enc, const float* __restrict__ b_enc,
               const float* __restrict__ w_ro, const float* __restrict__ b_ro,
               float* __restrict__ out)
{
    const int tid  = threadIdx.x;      // 0..127
    const int wid  = tid >> 6;         // wave id: 0,1
    const int lane = tid & 63;
    const int col  = lane & 15;        // batch-in-tile (N) / weight row (A-m)
    const int quad = lane >> 4;        // 0..3
    const int base = blockIdx.x << 4;  // global batch base
    const int own  = wid;              // own K-chunk of h1/h2 (rows 32*wid..)
    const int oth  = 1 - wid;
    const int qh   = quad >> 1;        // write sub-chunk select
    const int qo   = 4*(quad & 1);     // write offset within 8-chunk

    // chunk-major: [kc][n][8 halves]; fragment read = &buf[kc][col][0]
    __shared__ __align__(16) _Float16 zbufH[4][16][8];    // z: K=32 -> 4 chunks
    __shared__ __align__(16) _Float16 zbufL[4][16][8];
    __shared__ __align__(16) _Float16 h1bufH[8][16][8];   // h: K=64 -> 8 chunks
    __shared__ __align__(16) _Float16 h1bufL[8][16][8];
    __shared__ __align__(16) _Float16 h2bufH[8][16][8];
    __shared__ __align__(16) _Float16 h2bufL[8][16][8];
    __shared__ __align__(16) float    dqbuf[16][4];
    __shared__ float robuf[16];

    // -------- weights -> f16 hi/lo A-fragments (this wave's halves) ---------
    half8v w1fH[2], w1fL[2];
    #pragma unroll
    for (int tt = 0; tt < 2; ++tt) {
        const int T = 2*wid + tt;
        const float* p = w1 + (16*T + col)*32 + quad*8;
        #pragma unroll
        for (int j = 0; j < 8; ++j) {
            _Float16 hi, lo; split_f16(p[j], hi, lo);
            w1fH[tt][j] = hi; w1fL[tt][j] = lo;
        }
    }
    // L2: own/other K-chunks (own = rows 32*wid of h1, i.e. kt = wid)
    half8v w2oH[2], w2oL[2], w2xH[2], w2xL[2];
    #pragma unroll
    for (int tt = 0; tt < 2; ++tt) {
        const int T = 2*wid + tt;
        {
            const float* p = w2 + (16*T + col)*64 + own*32 + quad*8;
            #pragma unroll
            for (int j = 0; j < 8; ++j) {
                _Float16 hi, lo; split_f16(p[j], hi, lo);
                w2oH[tt][j] = hi; w2oL[tt][j] = lo;
            }
        }
        {
            const float* p = w2 + (16*T + col)*64 + oth*32 + quad*8;
            #pragma unroll
            for (int j = 0; j < 8; ++j) {
                _Float16 hi, lo; split_f16(p[j], hi, lo);
                w2xH[tt][j] = hi; w2xL[tt][j] = lo;
            }
        }
    }
    // L3: rows (16*wid + col)*3 + c; own/other K-chunks of h2
    half8v w3oH[3], w3oL[3], w3xH[3], w3xL[3];
    #pragma unroll
    for (int c = 0; c < 3; ++c) {
        const int row = (16*wid + col)*3 + c;
        {
            const float* p = w3 + row*64 + own*32 + quad*8;
            #pragma unroll
            for (int j = 0; j < 8; ++j) {
                _Float16 hi, lo; split_f16(p[j], hi, lo);
                w3oH[c][j] = hi; w3oL[c][j] = lo;
            }
        }
        {
            const float* p = w3 + row*64 + oth*32 + quad*8;
            #pragma unroll
            for (int j = 0; j < 8; ++j) {
                _Float16 hi, lo; split_f16(p[j], hi, lo);
                w3xH[c][j] = hi; w3xL[c][j] = lo;
            }
        }
    }

    // biases in C-layout
    float b1c[2][4], b2c[2][4], b3c[3][4];
    #pragma unroll
    for (int tt = 0; tt < 2; ++tt) {
        const int T = 2*wid + tt;
        #pragma unroll
        for (int r = 0; r < 4; ++r) {
            b1c[tt][r] = b1[16*T + 4*quad + r];
            b2c[tt][r] = b2[16*T + 4*quad + r];
        }
    }
    #pragma unroll
    for (int c = 0; c < 3; ++c)
        #pragma unroll
        for (int r = 0; r < 4; ++r)
            b3c[c][r] = b3[(16*wid + 4*quad + r)*3 + c];

    // state z rows owned by this wave: h = 16*wid + 4*quad + r
    float z[4];
    #pragma unroll
    for (int r = 0; r < 4; ++r) {
        const int h = 16*wid + 4*quad + r;
        z[r] = w_enc[h] + b_enc[h];   // encoder([1.0])
    }
    const float dt = times[1] - times[0];

    // dq staging: threads 0..47 (wave 0) fetch one (b,c) stream
    const int lcl = tid < 48 ? tid : 47;
    const int bl  = lcl / 3;
    const int cc  = lcl - 3*bl;
    const float* gp = grads + (long)(base + bl)*(TT*3) + cc;
    const bool dqact = tid < 48;
    float dqreg = gp[0];

    static constexpr float AT[6][5] = {
        {0.f, 0.f, 0.f, 0.f, 0.f},
        {0.161f, 0.f, 0.f, 0.f, 0.f},
        {-0.008480655492356989f, 0.335480655492357f, 0.f, 0.f, 0.f},
        {2.8971530571054935f, -6.359448489975075f, 4.3622954328695815f, 0.f, 0.f},
        {5.325864828439257f, -11.748883564062828f, 7.4955393428898365f,
         -0.09249506636175525f, 0.f},
        {5.86145544294642f, -12.92096931784711f, 8.159367898576159f,
         -0.071584973281401f, -0.028269050394068383f}};
    static constexpr float BT[6] = {
        0.09646076681806523f, 0.01f, 0.4798896504144996f, 1.379008574103742f,
        -3.290069515436081f, 2.324710524099774f};

    float kk[6][4];
    float dq0 = 0.f, dq1 = 0.f, dq2 = 0.f;

    for (int n = 0; n < NSTEP; ++n) {
        if (dqact) *(&dqbuf[0][0] + (bl*4 + cc)) = dqreg * dt;

        #pragma unroll
        for (int s = 0; s < 6; ++s) {
            // ---- za (own 16 z rows) + publish ----
            float za[4];
            #pragma unroll
            for (int r = 0; r < 4; ++r) {
                float v = z[r];
                #pragma unroll
                for (int j = 0; j < s; ++j) v += AT[s][j] * kk[j][r];
                za[r] = v;
            }
            {
                uint2 uH, uL;
                split_pack4(za[0], za[1], za[2], za[3], uH, uL);
                *(uint2*)&zbufH[2*wid + qh][col][qo] = uH;
                *(uint2*)&zbufL[2*wid + qh][col][qo] = uL;
            }
            __syncthreads();                                   // B0: za ready
            if (s == 0) {
                const float4 dv = *(const float4*)&dqbuf[col][0];
                dq0 = dv.x; dq1 = dv.y; dq2 = dv.z;
                const int nn = (n + 1 < NSTEP) ? (n + 1) : (NSTEP - 1);
                dqreg = gp[nn * 3];          // prefetch next step's gradient
            }
            const half8v zfH = *(const half8v*)&zbufH[quad][col][0];
            const half8v zfL = *(const half8v*)&zbufL[quad][col][0];

            // ---- layer 1 (K=32, unsplittable): this wave's 32 rows ----
            __builtin_amdgcn_s_setprio(1);
            #pragma unroll
            for (int tt = 0; tt < 2; ++tt) {
                floatx4 acc = {b1c[tt][0], b1c[tt][1], b1c[tt][2], b1c[tt][3]};
                acc = __builtin_amdgcn_mfma_f32_16x16x32_f16(w1fH[tt], zfH, acc, 0, 0, 0);
                acc = __builtin_amdgcn_mfma_f32_16x16x32_f16(w1fL[tt], zfH, acc, 0, 0, 0);
                acc = __builtin_amdgcn_mfma_f32_16x16x32_f16(w1fH[tt], zfL, acc, 0, 0, 0);
                uint2 uH, uL;
                split_pack4(fast_tanh(acc[0]), fast_tanh(acc[1]),
                            fast_tanh(acc[2]), fast_tanh(acc[3]), uH, uL);
                *(uint2*)&h1bufH[4*wid + 2*tt + qh][col][qo] = uH;
                *(uint2*)&h1bufL[4*wid + 2*tt + qh][col][qo] = uL;
            }
            // ---- layer 2, own chunk, tt=0 slice (pre-B1: absorbs skew) ----
            const half8v h1oH = *(const half8v*)&h1bufH[4*own + quad][col][0];
            const half8v h1oL = *(const half8v*)&h1bufL[4*own + quad][col][0];
            floatx4 acc2[2];
            {
                floatx4 acc = {b2c[0][0], b2c[0][1], b2c[0][2], b2c[0][3]};
                acc = __builtin_amdgcn_mfma_f32_16x16x32_f16(w2oH[0], h1oH, acc, 0, 0, 0);
                acc = __builtin_amdgcn_mfma_f32_16x16x32_f16(w2oL[0], h1oH, acc, 0, 0, 0);
                acc = __builtin_amdgcn_mfma_f32_16x16x32_f16(w2oH[0], h1oL, acc, 0, 0, 0);
                acc2[0] = acc;
            }
            __builtin_amdgcn_s_setprio(0);
            __syncthreads();                                   // B1: h1 ready
            // ---- post-B1: issue partner reads, cover with own tt=1 ----
            const half8v h1xH = *(const half8v*)&h1bufH[4*oth + quad][col][0];
            const half8v h1xL = *(const half8v*)&h1bufL[4*oth + quad][col][0];
            __builtin_amdgcn_s_setprio(1);
            {
                floatx4 acc = {b2c[1][0], b2c[1][1], b2c[1][2], b2c[1][3]};
                acc = __builtin_amdgcn_mfma_f32_16x16x32_f16(w2oH[1], h1oH, acc, 0, 0, 0);
                acc = __builtin_amdgcn_mfma_f32_16x16x32_f16(w2oL[1], h1oH, acc, 0, 0, 0);
                acc = __builtin_amdgcn_mfma_f32_16x16x32_f16(w2oH[1], h1oL, acc, 0, 0, 0);
                acc2[1] = acc;
            }
            #pragma unroll
            for (int tt = 0; tt < 2; ++tt) {
                floatx4 acc = acc2[tt];
                acc = __builtin_amdgcn_mfma_f32_16x16x32_f16(w2xH[tt], h1xH, acc, 0, 0, 0);
                acc = __builtin_amdgcn_mfma_f32_16x16x32_f16(w2xL[tt], h1xH, acc, 0, 0, 0);
                acc = __builtin_amdgcn_mfma_f32_16x16x32_f16(w2xH[tt], h1xL, acc, 0, 0, 0);
                uint2 uH, uL;
                split_pack4(fast_tanh(acc[0]), fast_tanh(acc[1]),
                            fast_tanh(acc[2]), fast_tanh(acc[3]), uH, uL);
                *(uint2*)&h2bufH[4*wid + 2*tt + qh][col][qo] = uH;
                *(uint2*)&h2bufL[4*wid + 2*tt + qh][col][qo] = uL;
            }
            // ---- layer 3, own chunk, c=0 slice (pre-B2: absorbs skew) ----
            const half8v h2oH = *(const half8v*)&h2bufH[4*own + quad][col][0];
            const half8v h2oL = *(const half8v*)&h2bufL[4*own + quad][col][0];
            floatx4 acc3[3];
            {
                floatx4 acc = {b3c[0][0], b3c[0][1], b3c[0][2], b3c[0][3]};
                acc = __builtin_amdgcn_mfma_f32_16x16x32_f16(w3oH[0], h2oH, acc, 0, 0, 0);
                acc = __builtin_amdgcn_mfma_f32_16x16x32_f16(w3oL[0], h2oH, acc, 0, 0, 0);
                acc = __builtin_amdgcn_mfma_f32_16x16x32_f16(w3oH[0], h2oL, acc, 0, 0, 0);
                acc3[0] = acc;
            }
            __builtin_amdgcn_s_setprio(0);
            __syncthreads();                                   // B2: h2 ready
            // ---- post-B2: issue partner reads, cover with own c=1,2 ----
            const half8v h2xH = *(const half8v*)&h2bufH[4*oth + quad][col][0];
            const half8v h2xL = *(const half8v*)&h2bufL[4*oth + quad][col][0];
            __builtin_amdgcn_s_setprio(1);
            #pragma unroll
            for (int c = 1; c < 3; ++c) {
                floatx4 acc = {b3c[c][0], b3c[c][1], b3c[c][2], b3c[c][3]};
                acc = __builtin_amdgcn_mfma_f32_16x16x32_f16(w3oH[c], h2oH, acc, 0, 0, 0);
                acc = __builtin_amdgcn_mfma_f32_16x16x32_f16(w3oL[c], h2oH, acc, 0, 0, 0);
                acc = __builtin_amdgcn_mfma_f32_16x16x32_f16(w3oH[c], h2oL, acc, 0, 0, 0);
                acc3[c] = acc;
            }
            #pragma unroll
            for (int c = 0; c < 3; ++c) {
                acc3[c] = __builtin_amdgcn_mfma_f32_16x16x32_f16(w3xH[c], h2xH, acc3[c], 0, 0, 0);
                acc3[c] = __builtin_amdgcn_mfma_f32_16x16x32_f16(w3xL[c], h2xH, acc3[c], 0, 0, 0);
                acc3[c] = __builtin_amdgcn_mfma_f32_16x16x32_f16(w3xH[c], h2xL, acc3[c], 0, 0, 0);
            }
            __builtin_amdgcn_s_setprio(0);
            #pragma unroll
            for (int r = 0; r < 4; ++r)
                kk[s][r] = acc3[0][r]*dq0 + acc3[1][r]*dq1 + acc3[2][r]*dq2;
        }

        // z += sum_i B_i * k_i
        #pragma unroll
        for (int r = 0; r < 4; ++r) {
            float v = z[r];
            #pragma unroll
            for (int j = 0; j < 6; ++j) v += BT[j] * kk[j][r];
            z[r] = v;
        }
    }

    // ---- readout: logit[b] = sum_h z[h][b]*w_ro[h] + b_ro; out = sigmoid ----
    float part = 0.f;
    #pragma unroll
    for (int r = 0; r < 4; ++r)
        part += z[r] * w_ro[16*wid + 4*quad + r];
    part += __shfl_xor(part, 16, 64);
    part += __shfl_xor(part, 32, 64);
    if (wid == 1 && lane < 16) robuf[col] = part;
    __syncthreads();
    if (wid == 0 && lane < 16) {
        const float x = part + robuf[col] + b_ro[0];
        out[base + col] = FAST_RCP(1.0f + FAST_EXP2(-1.4426950408889634f * x));
    }
}

extern "C" void kernel_launch(void* const* d_in, const int* in_sizes, int n_in,
                              void* d_out, int out_size, void* d_ws, size_t ws_size,
                              hipStream_t stream) {
    const float* times = (const float*)d_in[0];
    const float* grads = (const float*)d_in[1];
    const float* w1    = (const float*)d_in[2];
    const float* b1    = (const float*)d_in[3];
    const float* w2    = (const float*)d_in[4];
    const float* b2    = (const float*)d_in[5];
    const float* w3    = (const float*)d_in[6];
    const float* b3    = (const float*)d_in[7];
    const float* w_enc = (const float*)d_in[8];
    const float* b_enc = (const float*)d_in[9];
    const float* w_ro  = (const float*)d_in[10];
    const float* b_ro  = (const float*)d_in[11];

    const int B = in_sizes[1] / (TT * 3);   // 16384
    dim3 grid(B / 16), block(128);
    hipLaunchKernelGGL(cde_fused, grid, block, 0, stream,
                       times, grads, w1, b1, w2, b2, w3, b3,
                       w_enc, b_enc, w_ro, b_ro, (float*)d_out);
}

// Round 14
// 3283.401 us; speedup vs baseline: 1.5922x; 1.2770x over previous
//
#include <hip/hip_runtime.h>

#define TT 512
#define NSTEP 511

typedef _Float16 half8v __attribute__((ext_vector_type(8)));
typedef float floatx4 __attribute__((ext_vector_type(4)));

#if __has_builtin(__builtin_amdgcn_exp2f)
#define FAST_EXP2 __builtin_amdgcn_exp2f
#else
#define FAST_EXP2 exp2f
#endif
#if __has_builtin(__builtin_amdgcn_rcpf)
#define FAST_RCP __builtin_amdgcn_rcpf
#else
#define FAST_RCP(x) (1.0f/(x))
#endif

__device__ __forceinline__ float fast_tanh(float x) {
    float e = FAST_EXP2(x * 2.885390081777927f);
    return 1.0f - 2.0f * FAST_RCP(1.0f + e);
}

__device__ __forceinline__ void split_f16(float x, _Float16& hi, _Float16& lo) {
    hi = (_Float16)x;
    lo = (_Float16)(x - (float)hi);   // exact residual, then f16 round
}

// Full hi/lo pack (za path; L1 keeps the 3-term split).
__device__ __forceinline__ void split_pack4(const float x0, const float x1,
                                            const float x2, const float x3,
                                            uint2& uH, uint2& uL) {
    auto h01 = __builtin_amdgcn_cvt_pkrtz(x0, x1);   // __fp16 x2
    auto h23 = __builtin_amdgcn_cvt_pkrtz(x2, x3);
    auto l01 = __builtin_amdgcn_cvt_pkrtz(x0 - (float)h01[0], x1 - (float)h01[1]);
    auto l23 = __builtin_amdgcn_cvt_pkrtz(x2 - (float)h23[0], x3 - (float)h23[1]);
    uH.x = __builtin_bit_cast(unsigned int, h01);
    uH.y = __builtin_bit_cast(unsigned int, h23);
    uL.x = __builtin_bit_cast(unsigned int, l01);
    uL.y = __builtin_bit_cast(unsigned int, l23);
}

// Hi-only pack (activation path; residual term dropped for L2/L3).
__device__ __forceinline__ uint2 pack4h(const float x0, const float x1,
                                        const float x2, const float x3) {
    auto h01 = __builtin_amdgcn_cvt_pkrtz(x0, x1);
    auto h23 = __builtin_amdgcn_cvt_pkrtz(x2, x3);
    uint2 u;
    u.x = __builtin_bit_cast(unsigned int, h01);
    u.y = __builtin_bit_cast(unsigned int, h23);
    return u;
}

// r14: DROP the activation-residual MFMA term for L2/L3 (r13 skeleton, 4193 µs).
// r13 showed conflicts off the critical path; remaining idle = dependency
// chain around a 36-MFMA/wave floor. Precision analysis: L2/L3 inputs are
// tanh outputs (|h|<=1 -> |h_lo|<=2^-12); dropping Whi*h_lo gives preact
// error ~2^-14 (L2) and kk error ~2e-5/step (L3) -> random-walk ~1e-3 in z
// over 511 steps -> ~2.5e-4 at the sigmoid, an order below the schedule-
// invariant absmax 2^-8. L1's input z is unbounded: keeps all 3 terms.
// Per wave: L1 6 + L2 8 + L3 12 = 26 MFMA (was 36). h1/h2 LO buffers
// deleted (LDS/read/pack traffic halves on the activation path).
// Straddle/setprio/chunk-major layout unchanged from r13.
// A-frag: A[m=lane&15][k=quad*8+j]; B-frag: B[k=quad*8+j][n=lane&15];
// C: col(N)=lane&15, row(M)=quad*4+reg.
__global__ __launch_bounds__(128, 2)
void cde_fused(const float* __restrict__ times,
               const float* __restrict__ grads,   // (B, T, 3)
               const float* __restrict__ w1, const float* __restrict__ b1,
               const float* __restrict__ w2, const float* __restrict__ b2,
               const float* __restrict__ w3, const float* __restrict__ b3,
               const float* __restrict__ w_enc, const float* __restrict__ b_enc,
               const float* __restrict__ w_ro, const float* __restrict__ b_ro,
               float* __restrict__ out)
{
    const int tid  = threadIdx.x;      // 0..127
    const int wid  = tid >> 6;         // wave id: 0,1
    const int lane = tid & 63;
    const int col  = lane & 15;        // batch-in-tile (N) / weight row (A-m)
    const int quad = lane >> 4;        // 0..3
    const int base = blockIdx.x << 4;  // global batch base
    const int own  = wid;              // own K-chunk of h1/h2 (rows 32*wid..)
    const int oth  = 1 - wid;
    const int qh   = quad >> 1;        // write sub-chunk select
    const int qo   = 4*(quad & 1);     // write offset within 8-chunk

    // chunk-major: [kc][n][8 halves]; fragment read = &buf[kc][col][0]
    __shared__ __align__(16) _Float16 zbufH[4][16][8];    // z: K=32 -> 4 chunks
    __shared__ __align__(16) _Float16 zbufL[4][16][8];
    __shared__ __align__(16) _Float16 h1bufH[8][16][8];   // h: K=64 -> 8 chunks
    __shared__ __align__(16) _Float16 h2bufH[8][16][8];
    __shared__ __align__(16) float    dqbuf[16][4];
    __shared__ float robuf[16];

    // -------- weights -> f16 hi/lo A-fragments (this wave's halves) ---------
    half8v w1fH[2], w1fL[2];
    #pragma unroll
    for (int tt = 0; tt < 2; ++tt) {
        const int T = 2*wid + tt;
        const float* p = w1 + (16*T + col)*32 + quad*8;
        #pragma unroll
        for (int j = 0; j < 8; ++j) {
            _Float16 hi, lo; split_f16(p[j], hi, lo);
            w1fH[tt][j] = hi; w1fL[tt][j] = lo;
        }
    }
    // L2: own/other K-chunks (own = rows 32*wid of h1, i.e. kt = wid)
    half8v w2oH[2], w2oL[2], w2xH[2], w2xL[2];
    #pragma unroll
    for (int tt = 0; tt < 2; ++tt) {
        const int T = 2*wid + tt;
        {
            const float* p = w2 + (16*T + col)*64 + own*32 + quad*8;
            #pragma unroll
            for (int j = 0; j < 8; ++j) {
                _Float16 hi, lo; split_f16(p[j], hi, lo);
                w2oH[tt][j] = hi; w2oL[tt][j] = lo;
            }
        }
        {
            const float* p = w2 + (16*T + col)*64 + oth*32 + quad*8;
            #pragma unroll
            for (int j = 0; j < 8; ++j) {
                _Float16 hi, lo; split_f16(p[j], hi, lo);
                w2xH[tt][j] = hi; w2xL[tt][j] = lo;
            }
        }
    }
    // L3: rows (16*wid + col)*3 + c; own/other K-chunks of h2
    half8v w3oH[3], w3oL[3], w3xH[3], w3xL[3];
    #pragma unroll
    for (int c = 0; c < 3; ++c) {
        const int row = (16*wid + col)*3 + c;
        {
            const float* p = w3 + row*64 + own*32 + quad*8;
            #pragma unroll
            for (int j = 0; j < 8; ++j) {
                _Float16 hi, lo; split_f16(p[j], hi, lo);
                w3oH[c][j] = hi; w3oL[c][j] = lo;
            }
        }
        {
            const float* p = w3 + row*64 + oth*32 + quad*8;
            #pragma unroll
            for (int j = 0; j < 8; ++j) {
                _Float16 hi, lo; split_f16(p[j], hi, lo);
                w3xH[c][j] = hi; w3xL[c][j] = lo;
            }
        }
    }

    // biases in C-layout
    float b1c[2][4], b2c[2][4], b3c[3][4];
    #pragma unroll
    for (int tt = 0; tt < 2; ++tt) {
        const int T = 2*wid + tt;
        #pragma unroll
        for (int r = 0; r < 4; ++r) {
            b1c[tt][r] = b1[16*T + 4*quad + r];
            b2c[tt][r] = b2[16*T + 4*quad + r];
        }
    }
    #pragma unroll
    for (int c = 0; c < 3; ++c)
        #pragma unroll
        for (int r = 0; r < 4; ++r)
            b3c[c][r] = b3[(16*wid + 4*quad + r)*3 + c];

    // state z rows owned by this wave: h = 16*wid + 4*quad + r
    float z[4];
    #pragma unroll
    for (int r = 0; r < 4; ++r) {
        const int h = 16*wid + 4*quad + r;
        z[r] = w_enc[h] + b_enc[h];   // encoder([1.0])
    }
    const float dt = times[1] - times[0];

    // dq staging: threads 0..47 (wave 0) fetch one (b,c) stream
    const int lcl = tid < 48 ? tid : 47;
    const int bl  = lcl / 3;
    const int cc  = lcl - 3*bl;
    const float* gp = grads + (long)(base + bl)*(TT*3) + cc;
    const bool dqact = tid < 48;
    float dqreg = gp[0];

    static constexpr float AT[6][5] = {
        {0.f, 0.f, 0.f, 0.f, 0.f},
        {0.161f, 0.f, 0.f, 0.f, 0.f},
        {-0.008480655492356989f, 0.335480655492357f, 0.f, 0.f, 0.f},
        {2.8971530571054935f, -6.359448489975075f, 4.3622954328695815f, 0.f, 0.f},
        {5.325864828439257f, -11.748883564062828f, 7.4955393428898365f,
         -0.09249506636175525f, 0.f},
        {5.86145544294642f, -12.92096931784711f, 8.159367898576159f,
         -0.071584973281401f, -0.028269050394068383f}};
    static constexpr float BT[6] = {
        0.09646076681806523f, 0.01f, 0.4798896504144996f, 1.379008574103742f,
        -3.290069515436081f, 2.324710524099774f};

    float kk[6][4];
    float dq0 = 0.f, dq1 = 0.f, dq2 = 0.f;

    for (int n = 0; n < NSTEP; ++n) {
        if (dqact) *(&dqbuf[0][0] + (bl*4 + cc)) = dqreg * dt;

        #pragma unroll
        for (int s = 0; s < 6; ++s) {
            // ---- za (own 16 z rows) + publish (full hi/lo: L1 is 3-term) ----
            float za[4];
            #pragma unroll
            for (int r = 0; r < 4; ++r) {
                float v = z[r];
                #pragma unroll
                for (int j = 0; j < s; ++j) v += AT[s][j] * kk[j][r];
                za[r] = v;
            }
            {
                uint2 uH, uL;
                split_pack4(za[0], za[1], za[2], za[3], uH, uL);
                *(uint2*)&zbufH[2*wid + qh][col][qo] = uH;
                *(uint2*)&zbufL[2*wid + qh][col][qo] = uL;
            }
            __syncthreads();                                   // B0: za ready
            if (s == 0) {
                const float4 dv = *(const float4*)&dqbuf[col][0];
                dq0 = dv.x; dq1 = dv.y; dq2 = dv.z;
                const int nn = (n + 1 < NSTEP) ? (n + 1) : (NSTEP - 1);
                dqreg = gp[nn * 3];          // prefetch next step's gradient
            }
            const half8v zfH = *(const half8v*)&zbufH[quad][col][0];
            const half8v zfL = *(const half8v*)&zbufL[quad][col][0];

            // ---- layer 1 (3-term, K=32): this wave's 32 rows ----
            __builtin_amdgcn_s_setprio(1);
            #pragma unroll
            for (int tt = 0; tt < 2; ++tt) {
                floatx4 acc = {b1c[tt][0], b1c[tt][1], b1c[tt][2], b1c[tt][3]};
                acc = __builtin_amdgcn_mfma_f32_16x16x32_f16(w1fH[tt], zfH, acc, 0, 0, 0);
                acc = __builtin_amdgcn_mfma_f32_16x16x32_f16(w1fL[tt], zfH, acc, 0, 0, 0);
                acc = __builtin_amdgcn_mfma_f32_16x16x32_f16(w1fH[tt], zfL, acc, 0, 0, 0);
                const uint2 uH = pack4h(fast_tanh(acc[0]), fast_tanh(acc[1]),
                                        fast_tanh(acc[2]), fast_tanh(acc[3]));
                *(uint2*)&h1bufH[4*wid + 2*tt + qh][col][qo] = uH;
            }
            // ---- layer 2, own chunk, tt=0 slice (pre-B1: absorbs skew) ----
            const half8v h1oH = *(const half8v*)&h1bufH[4*own + quad][col][0];
            floatx4 acc2[2];
            {
                floatx4 acc = {b2c[0][0], b2c[0][1], b2c[0][2], b2c[0][3]};
                acc = __builtin_amdgcn_mfma_f32_16x16x32_f16(w2oH[0], h1oH, acc, 0, 0, 0);
                acc = __builtin_amdgcn_mfma_f32_16x16x32_f16(w2oL[0], h1oH, acc, 0, 0, 0);
                acc2[0] = acc;
            }
            __builtin_amdgcn_s_setprio(0);
            __syncthreads();                                   // B1: h1 ready
            // ---- post-B1: issue partner read, cover with own tt=1 ----
            const half8v h1xH = *(const half8v*)&h1bufH[4*oth + quad][col][0];
            __builtin_amdgcn_s_setprio(1);
            {
                floatx4 acc = {b2c[1][0], b2c[1][1], b2c[1][2], b2c[1][3]};
                acc = __builtin_amdgcn_mfma_f32_16x16x32_f16(w2oH[1], h1oH, acc, 0, 0, 0);
                acc = __builtin_amdgcn_mfma_f32_16x16x32_f16(w2oL[1], h1oH, acc, 0, 0, 0);
                acc2[1] = acc;
            }
            #pragma unroll
            for (int tt = 0; tt < 2; ++tt) {
                floatx4 acc = acc2[tt];
                acc = __builtin_amdgcn_mfma_f32_16x16x32_f16(w2xH[tt], h1xH, acc, 0, 0, 0);
                acc = __builtin_amdgcn_mfma_f32_16x16x32_f16(w2xL[tt], h1xH, acc, 0, 0, 0);
                const uint2 uH = pack4h(fast_tanh(acc[0]), fast_tanh(acc[1]),
                                        fast_tanh(acc[2]), fast_tanh(acc[3]));
                *(uint2*)&h2bufH[4*wid + 2*tt + qh][col][qo] = uH;
            }
            // ---- layer 3, own chunk, c=0 slice (pre-B2: absorbs skew) ----
            const half8v h2oH = *(const half8v*)&h2bufH[4*own + quad][col][0];
            floatx4 acc3[3];
            {
                floatx4 acc = {b3c[0][0], b3c[0][1], b3c[0][2], b3c[0][3]};
                acc = __builtin_amdgcn_mfma_f32_16x16x32_f16(w3oH[0], h2oH, acc, 0, 0, 0);
                acc = __builtin_amdgcn_mfma_f32_16x16x32_f16(w3oL[0], h2oH, acc, 0, 0, 0);
                acc3[0] = acc;
            }
            __builtin_amdgcn_s_setprio(0);
            __syncthreads();                                   // B2: h2 ready
            // ---- post-B2: issue partner read, cover with own c=1,2 ----
            const half8v h2xH = *(const half8v*)&h2bufH[4*oth + quad][col][0];
            __builtin_amdgcn_s_setprio(1);
            #pragma unroll
            for (int c = 1; c < 3; ++c) {
                floatx4 acc = {b3c[c][0], b3c[c][1], b3c[c][2], b3c[c][3]};
                acc = __builtin_amdgcn_mfma_f32_16x16x32_f16(w3oH[c], h2oH, acc, 0, 0, 0);
                acc = __builtin_amdgcn_mfma_f32_16x16x32_f16(w3oL[c], h2oH, acc, 0, 0, 0);
                acc3[c] = acc;
            }
            #pragma unroll
            for (int c = 0; c < 3; ++c) {
                acc3[c] = __builtin_amdgcn_mfma_f32_16x16x32_f16(w3xH[c], h2xH, acc3[c], 0, 0, 0);
                acc3[c] = __builtin_amdgcn_mfma_f32_16x16x32_f16(w3xL[c], h2xH, acc3[c], 0, 0, 0);
            }
            __builtin_amdgcn_s_setprio(0);
            #pragma unroll
            for (int r = 0; r < 4; ++r)
                kk[s][r] = acc3[0][r]*dq0 + acc3[1][r]*dq1 + acc3[2][r]*dq2;
        }

        // z += sum_i B_i * k_i
        #pragma unroll
        for (int r = 0; r < 4; ++r) {
            float v = z[r];
            #pragma unroll
            for (int j = 0; j < 6; ++j) v += BT[j] * kk[j][r];
            z[r] = v;
        }
    }

    // ---- readout: logit[b] = sum_h z[h][b]*w_ro[h] + b_ro; out = sigmoid ----
    float part = 0.f;
    #pragma unroll
    for (int r = 0; r < 4; ++r)
        part += z[r] * w_ro[16*wid + 4*quad + r];
    part += __shfl_xor(part, 16, 64);
    part += __shfl_xor(part, 32, 64);
    if (wid == 1 && lane < 16) robuf[col] = part;
    __syncthreads();
    if (wid == 0 && lane < 16) {
        const float x = part + robuf[col] + b_ro[0];
        out[base + col] = FAST_RCP(1.0f + FAST_EXP2(-1.4426950408889634f * x));
    }
}

extern "C" void kernel_launch(void* const* d_in, const int* in_sizes, int n_in,
                              void* d_out, int out_size, void* d_ws, size_t ws_size,
                              hipStream_t stream) {
    const float* times = (const float*)d_in[0];
    const float* grads = (const float*)d_in[1];
    const float* w1    = (const float*)d_in[2];
    const float* b1    = (const float*)d_in[3];
    const float* w2    = (const float*)d_in[4];
    const float* b2    = (const float*)d_in[5];
    const float* w3    = (const float*)d_in[6];
    const float* b3    = (const float*)d_in[7];
    const float* w_enc = (const float*)d_in[8];
    const float* b_enc = (const float*)d_in[9];
    const float* w_ro  = (const float*)d_in[10];
    const float* b_ro  = (const float*)d_in[11];

    const int B = in_sizes[1] / (TT * 3);   // 16384
    dim3 grid(B / 16), block(128);
    hipLaunchKernelGGL(cde_fused, grid, block, 0, stream,
                       times, grads, w1, b1, w2, b2, w3, b3,
                       w_enc, b_enc, w_ro, b_ro, (float*)d_out);
}